// Round 3
// baseline (378.053 us; speedup 1.0000x reference)
//
#include <hip/hip_runtime.h>

// CausalSelfAttention: B=2, S=2048, D=1024, H=16, HD=64
#define B_  2
#define S_  2048
#define D_  1024
#define H_  16
#define HD_ 64
#define TD_ 3072
#define M_  (B_*S_)   // 4096

using bf16x8 = __attribute__((ext_vector_type(8))) short;   // 8 bf16 = 4 VGPRs
using f32x4  = __attribute__((ext_vector_type(4))) float;   // MFMA C/D

typedef __attribute__((address_space(1))) unsigned int uint_g;
typedef __attribute__((address_space(3))) unsigned int uint_l;

#define MFMA __builtin_amdgcn_mfma_f32_16x16x32_bf16

static __device__ __forceinline__ short f2bf(float f) {
    unsigned u = __float_as_uint(f);
    u += 0x7FFFu + ((u >> 16) & 1u);   // round-to-nearest-even
    return (short)(u >> 16);
}
static __device__ __forceinline__ unsigned pack2bf(float a, float b) {
    return (unsigned)(unsigned short)f2bf(a) | ((unsigned)(unsigned short)f2bf(b) << 16);
}
// async global->LDS, 16B/lane; LDS dest = uniform base + lane*16 (m97/m104 semantics)
static __device__ __forceinline__ void gload_lds16(const short* g, short* l) {
    __builtin_amdgcn_global_load_lds((const uint_g*)g, (uint_l*)l, 16, 0, 0);
}

// ---------------------------------------------------------------------------
// cast x (fp32) -> bf16
// ---------------------------------------------------------------------------
__global__ void cast_x_kernel(const float* __restrict__ x, short* __restrict__ xb, int n4) {
    int i = blockIdx.x * blockDim.x + threadIdx.x;
    if (i >= n4) return;
    float4 v = *((const float4*)x + i);
    short4 o;
    o.x = f2bf(v.x); o.y = f2bf(v.y); o.z = f2bf(v.z); o.w = f2bf(v.w);
    *((short4*)xb + i) = o;
}

// ---------------------------------------------------------------------------
// W [K][N] fp32 -> Wt [N][K] bf16
// ---------------------------------------------------------------------------
__global__ __launch_bounds__(256)
void wtrans_kernel(const float* __restrict__ W, short* __restrict__ Wt, int K, int N) {
    __shared__ float T[32][33];
    int n0 = blockIdx.x * 32, k0 = blockIdx.y * 32;
    int tx = threadIdx.x & 31, ty = threadIdx.x >> 5;
    #pragma unroll
    for (int i = 0; i < 4; ++i)
        T[ty + i * 8][tx] = W[(size_t)(k0 + ty + i * 8) * N + n0 + tx];
    __syncthreads();
    #pragma unroll
    for (int i = 0; i < 4; ++i)
        Wt[(size_t)(n0 + ty + i * 8) * K + k0 + tx] = f2bf(T[tx][ty + i * 8]);
}

// ---------------------------------------------------------------------------
// V [B,H,S,HD] bf16 -> Vt [B,H,HD,S] bf16
// ---------------------------------------------------------------------------
__global__ __launch_bounds__(256)
void vtrans_kernel(const short* __restrict__ V, short* __restrict__ Vt) {
    __shared__ short T[32][33];
    int p  = blockIdx.z;
    int s0 = blockIdx.x * 32;
    int d0 = blockIdx.y * 32;
    int tx = threadIdx.x & 31, ty = threadIdx.x >> 5;
    const short* Vp  = V  + (size_t)p * S_ * HD_;
    short*       Vtp = Vt + (size_t)p * HD_ * S_;
    #pragma unroll
    for (int i = 0; i < 4; ++i)
        T[ty + i * 8][tx] = Vp[(s0 + ty + i * 8) * HD_ + d0 + tx];
    __syncthreads();
    #pragma unroll
    for (int i = 0; i < 4; ++i)
        Vtp[(size_t)(d0 + ty + i * 8) * S_ + s0 + tx] = T[tx][ty + i * 8];
}

// ---------------------------------------------------------------------------
// bf16 MFMA GEMM, m97 structure: 128x128 tile, BK=32, global_load_lds w=16.
// MODE 0: fp32 C + bias.  MODE 1: scatter Q(scaled)/K/V bf16 [B,H,S,HD].
// ---------------------------------------------------------------------------
template<int MODE>
__global__ __launch_bounds__(256)
void gemm_mfma_kernel(const short* __restrict__ A, const short* __restrict__ Bt,
                      const float* __restrict__ bias, float* __restrict__ Cf,
                      short* __restrict__ Qo, short* __restrict__ Ko, short* __restrict__ Vo,
                      int M, int N, int K) {
    __shared__ __align__(16) short As[128 * 32];
    __shared__ __align__(16) short Bs[128 * 32];

    const int tid  = threadIdx.x;
    const int w    = tid >> 6, lane = tid & 63;
    const int quad = lane >> 4, l16 = lane & 15;
    const int wr = (w >> 1) * 64, wc = (w & 1) * 64;
    const int rowBase = blockIdx.y * 128, colBase = blockIdx.x * 128;

    f32x4 acc[4][4];
    const f32x4 zero = {0.f, 0.f, 0.f, 0.f};
    #pragma unroll
    for (int i = 0; i < 4; ++i)
        #pragma unroll
        for (int j = 0; j < 4; ++j) acc[i][j] = zero;

    const int srow = lane >> 2;        // staging: lane's row within 16-row chunk
    const int scol = (lane & 3) * 8;   // staging: lane's k offset (shorts)

    for (int k0 = 0; k0 < K; k0 += 32) {
        __syncthreads();               // prior frag reads done before overwrite
        // wave w stages rows [w*16, +16) and [64+w*16, +16) of both tiles
        gload_lds16(A  + (size_t)(rowBase + w * 16 + srow)      * K + k0 + scol, &As[(w * 16) * 32]);
        gload_lds16(A  + (size_t)(rowBase + 64 + w * 16 + srow) * K + k0 + scol, &As[(64 + w * 16) * 32]);
        gload_lds16(Bt + (size_t)(colBase + w * 16 + srow)      * K + k0 + scol, &Bs[(w * 16) * 32]);
        gload_lds16(Bt + (size_t)(colBase + 64 + w * 16 + srow) * K + k0 + scol, &Bs[(64 + w * 16) * 32]);
        __syncthreads();               // vmcnt(0) drain -> data visible

        bf16x8 af[4], bf[4];
        #pragma unroll
        for (int t = 0; t < 4; ++t) {
            af[t] = *(const bf16x8*)&As[(wr + t * 16 + l16) * 32 + quad * 8];
            bf[t] = *(const bf16x8*)&Bs[(wc + t * 16 + l16) * 32 + quad * 8];
        }
        #pragma unroll
        for (int i = 0; i < 4; ++i)
            #pragma unroll
            for (int j = 0; j < 4; ++j)
                acc[i][j] = MFMA(af[i], bf[j], acc[i][j], 0, 0, 0);
    }

    if (MODE == 0) {
        #pragma unroll
        for (int i = 0; i < 4; ++i) {
            int row = rowBase + wr + i * 16 + quad * 4;
            #pragma unroll
            for (int j = 0; j < 4; ++j) {
                int col = colBase + wc + j * 16 + l16;
                float bv = bias[col];
                #pragma unroll
                for (int r = 0; r < 4; ++r)
                    Cf[(size_t)(row + r) * N + col] = acc[i][j][r] + bv;
            }
        }
    } else {
        #pragma unroll
        for (int j = 0; j < 4; ++j) {
            int col = colBase + wc + j * 16 + l16;
            int sel = col >> 10, cr = col & 1023;
            int h = cr >> 6, d = cr & 63;
            float bv  = bias[col];
            short* dst = (sel == 0) ? Qo : (sel == 1) ? Ko : Vo;
            float  scl = (sel == 0) ? 0.125f : 1.0f;   // softmax scale folded into Q
            #pragma unroll
            for (int i = 0; i < 4; ++i) {
                int row = rowBase + wr + i * 16 + quad * 4;
                #pragma unroll
                for (int r = 0; r < 4; ++r) {
                    int rw = row + r;
                    int bb = rw >> 11, s = rw & 2047;
                    dst[((size_t)(bb * H_ + h) * S_ + s) * HD_ + d] =
                        f2bf((acc[i][j][r] + bv) * scl);
                }
            }
        }
    }
}

// ---------------------------------------------------------------------------
// MFMA causal flash attention, zero-barrier design.
// Block = 4 independent waves; wave owns 16 q-rows. Computes S^T = K*Q^T
// (A=K, B=Q frags loaded DIRECTLY from global: layouts match b128 loads),
// per-lane scalar online softmax (q = l16; 2 shfl steps over quads),
// O^T = V^T * P^T (A=V^T from global; P^T via wave-private 2.3KB LDS buffer).
// No __syncthreads anywhere; LDS per block-iter = 16KB vs 96KB in R2.
// ---------------------------------------------------------------------------
__global__ __launch_bounds__(256)
void flash_mfma_kernel(const short* __restrict__ Qg, const short* __restrict__ Kg,
                       const short* __restrict__ Vtg, short* __restrict__ Ob) {
    __shared__ __align__(16) short Ps[4][16][72];   // wave-private P^T / O staging

    const int qt = (int)(gridDim.x - 1) - (int)blockIdx.x;  // heavy blocks first
    const int h = blockIdx.y, b = blockIdx.z;
    const int tid  = threadIdx.x;
    const int w    = tid >> 6, lane = tid & 63;
    const int quad = lane >> 4, l16 = lane & 15;
    const int qBase = qt * 64;
    const size_t plane = (size_t)(b * H_ + h) * S_ * HD_;

    // Q B-frags: lane n=l16 <-> q row, k=quad*8+j <-> d. Loaded once.
    const short* Qrow = Qg + plane + (size_t)(qBase + w * 16 + l16) * HD_ + quad * 8;
    const bf16x8 qb0 = *(const bf16x8*)(Qrow);
    const bf16x8 qb1 = *(const bf16x8*)(Qrow + 32);

    f32x4 o[4];
    const f32x4 zero = {0.f, 0.f, 0.f, 0.f};
    #pragma unroll
    for (int i = 0; i < 4; ++i) o[i] = zero;
    float m_r = -3.0e38f, l_r = 0.f;

    short* Pw = &Ps[w][0][0];
    const int q_glob = qBase + w * 16 + l16;

    for (int kt = 0; kt <= qt; ++kt) {
        const int kBase = kt * 64;

        // ---- S^T = K Q^T : A=K frag (m=kv=l16-row, k=d) straight from global
        f32x4 s[4];
        #pragma unroll
        for (int ct = 0; ct < 4; ++ct) {
            const short* Krow = Kg + plane + (size_t)(kBase + ct * 16 + l16) * HD_ + quad * 8;
            bf16x8 ka = *(const bf16x8*)(Krow);
            bf16x8 kb = *(const bf16x8*)(Krow + 32);
            f32x4 a = zero;
            a = MFMA(ka, qb0, a, 0, 0, 0);
            a = MFMA(kb, qb1, a, 0, 0, 0);
            s[ct] = a;
        }

        // ---- V^T A-frags (m=d=l16-row, k=kv) — issue early, independent
        bf16x8 vf[4][2];
        #pragma unroll
        for (int dt = 0; dt < 4; ++dt) {
            const short* Vrow = Vtg + plane + (size_t)(dt * 16 + l16) * S_ + kBase + quad * 8;
            vf[dt][0] = *(const bf16x8*)(Vrow);
            vf[dt][1] = *(const bf16x8*)(Vrow + 32);
        }

        // ---- causal mask (diagonal tile only): element kv=ct*16+quad*4+r, q=l16
        if (kt == qt) {
            #pragma unroll
            for (int ct = 0; ct < 4; ++ct) {
                int kv = kBase + ct * 16 + quad * 4;
                #pragma unroll
                for (int r = 0; r < 4; ++r)
                    if (kv + r > q_glob) s[ct][r] = -3.0e38f;
            }
        }

        // ---- online softmax: lane owns column q=l16 (16 kv values local)
        float mx = s[0][0];
        #pragma unroll
        for (int ct = 0; ct < 4; ++ct)
            #pragma unroll
            for (int r = 0; r < 4; ++r) mx = fmaxf(mx, s[ct][r]);
        mx = fmaxf(mx, __shfl_xor(mx, 16));
        mx = fmaxf(mx, __shfl_xor(mx, 32));
        float m_new = fmaxf(m_r, mx);
        float alpha = __expf(m_r - m_new);
        float rs = 0.f;
        #pragma unroll
        for (int ct = 0; ct < 4; ++ct) {
            float p0 = __expf(s[ct][0] - m_new);
            float p1 = __expf(s[ct][1] - m_new);
            float p2 = __expf(s[ct][2] - m_new);
            float p3 = __expf(s[ct][3] - m_new);
            rs += (p0 + p1) + (p2 + p3);
            uint2 uu;
            uu.x = pack2bf(p0, p1);
            uu.y = pack2bf(p2, p3);
            *(uint2*)&Pw[l16 * 72 + ct * 16 + quad * 4] = uu;   // P^T as [q][kv], b64
        }
        rs += __shfl_xor(rs, 16);
        rs += __shfl_xor(rs, 32);
        l_r = l_r * alpha + rs;
        m_r = m_new;
        #pragma unroll
        for (int dt = 0; dt < 4; ++dt)
            #pragma unroll
            for (int r = 0; r < 4; ++r) o[dt][r] *= alpha;

        // same-wave LDS write->read ordering: pin order + drain lgkmcnt
        __builtin_amdgcn_sched_barrier(0);
        __builtin_amdgcn_s_waitcnt(0xC07F);   // lgkmcnt(0) only
        __builtin_amdgcn_sched_barrier(0);

        // ---- O^T += V^T P^T : B=P^T frag (n=q=l16, k=kv) b128 from own rows
        #pragma unroll
        for (int kc = 0; kc < 2; ++kc) {
            bf16x8 pb = *(const bf16x8*)&Pw[l16 * 72 + kc * 32 + quad * 8];
            #pragma unroll
            for (int dt = 0; dt < 4; ++dt)
                o[dt] = MFMA(vf[dt][kc], pb, o[dt], 0, 0, 0);
        }
    }

    // ---- epilogue: O^T/l -> LDS transpose (bf16) -> coalesced b128 stores
    float inv_l = 1.0f / l_r;
    #pragma unroll
    for (int dt = 0; dt < 4; ++dt) {
        uint2 uu;
        uu.x = pack2bf(o[dt][0] * inv_l, o[dt][1] * inv_l);
        uu.y = pack2bf(o[dt][2] * inv_l, o[dt][3] * inv_l);
        *(uint2*)&Pw[l16 * 72 + dt * 16 + quad * 4] = uu;   // [q][d]
    }
    __builtin_amdgcn_sched_barrier(0);
    __builtin_amdgcn_s_waitcnt(0xC07F);
    __builtin_amdgcn_sched_barrier(0);
    #pragma unroll
    for (int pass = 0; pass < 2; ++pass) {
        int r  = pass * 8 + (lane >> 3);
        int cs = (lane & 7) * 8;
        uint4 vv = *(const uint4*)&Pw[r * 72 + cs];
        *(uint4*)(Ob + (size_t)(b * S_ + qBase + w * 16 + r) * D_ + h * HD_ + cs) = vv;
    }
}

// ---------------------------------------------------------------------------
extern "C" void kernel_launch(void* const* d_in, const int* in_sizes, int n_in,
                              void* d_out, int out_size, void* d_ws, size_t ws_size,
                              hipStream_t stream) {
    const float* x      = (const float*)d_in[0];
    const float* w_attn = (const float*)d_in[1];
    const float* b_attn = (const float*)d_in[2];
    const float* w_proj = (const float*)d_in[3];
    const float* b_proj = (const float*)d_in[4];
    float* out = (float*)d_out;

    char* ws = (char*)d_ws;
    short* xb  = (short*)ws; ws += (size_t)M_ * D_ * 2;
    short* wat = (short*)ws; ws += (size_t)TD_ * D_ * 2;
    short* wpt = (short*)ws; ws += (size_t)D_ * D_ * 2;
    short* qg  = (short*)ws; ws += (size_t)M_ * D_ * 2;
    short* kg  = (short*)ws; ws += (size_t)M_ * D_ * 2;
    short* vg  = (short*)ws; ws += (size_t)M_ * D_ * 2;
    short* vtg = (short*)ws; ws += (size_t)M_ * D_ * 2;
    short* atb = (short*)ws; ws += (size_t)M_ * D_ * 2;

    cast_x_kernel<<<(M_ * D_ / 4 + 255) / 256, 256, 0, stream>>>(x, xb, M_ * D_ / 4);
    wtrans_kernel<<<dim3(TD_ / 32, D_ / 32), 256, 0, stream>>>(w_attn, wat, D_, TD_);
    wtrans_kernel<<<dim3(D_ / 32, D_ / 32), 256, 0, stream>>>(w_proj, wpt, D_, D_);

    gemm_mfma_kernel<1><<<dim3(TD_ / 128, M_ / 128), 256, 0, stream>>>(
        xb, wat, b_attn, nullptr, qg, kg, vg, M_, TD_, D_);

    vtrans_kernel<<<dim3(S_ / 32, HD_ / 32, B_ * H_), 256, 0, stream>>>(vg, vtg);

    flash_mfma_kernel<<<dim3(S_ / 64, H_, B_), 256, 0, stream>>>(qg, kg, vtg, atb);

    gemm_mfma_kernel<0><<<dim3(D_ / 128, M_ / 128), 256, 0, stream>>>(
        atb, wpt, b_proj, out, nullptr, nullptr, nullptr, M_, D_, D_);
}

// Round 4
// 232.108 us; speedup vs baseline: 1.6288x; 1.6288x over previous
//
#include <hip/hip_runtime.h>

// CausalSelfAttention: B=2, S=2048, D=1024, H=16, HD=64
#define B_  2
#define S_  2048
#define D_  1024
#define H_  16
#define HD_ 64
#define TD_ 3072
#define M_  (B_*S_)   // 4096

using bf16x8 = __attribute__((ext_vector_type(8))) short;   // 8 bf16 = 4 VGPRs
using f32x4  = __attribute__((ext_vector_type(4))) float;   // MFMA C/D

typedef __attribute__((address_space(1))) unsigned int uint_g;
typedef __attribute__((address_space(3))) unsigned int uint_l;

#define MFMA __builtin_amdgcn_mfma_f32_16x16x32_bf16

static __device__ __forceinline__ short f2bf(float f) {
    unsigned u = __float_as_uint(f);
    u += 0x7FFFu + ((u >> 16) & 1u);   // round-to-nearest-even
    return (short)(u >> 16);
}
static __device__ __forceinline__ unsigned pack2bf(float a, float b) {
    return (unsigned)(unsigned short)f2bf(a) | ((unsigned)(unsigned short)f2bf(b) << 16);
}
// async global->LDS, 16B/lane; LDS dest = uniform base + lane*16 (m97/m104 semantics)
static __device__ __forceinline__ void gload_lds16(const short* g, short* l) {
    __builtin_amdgcn_global_load_lds((const uint_g*)g, (uint_l*)l, 16, 0, 0);
}

// ---------------------------------------------------------------------------
// cast x (fp32) -> bf16
// ---------------------------------------------------------------------------
__global__ void cast_x_kernel(const float* __restrict__ x, short* __restrict__ xb, int n4) {
    int i = blockIdx.x * blockDim.x + threadIdx.x;
    if (i >= n4) return;
    float4 v = *((const float4*)x + i);
    short4 o;
    o.x = f2bf(v.x); o.y = f2bf(v.y); o.z = f2bf(v.z); o.w = f2bf(v.w);
    *((short4*)xb + i) = o;
}

// ---------------------------------------------------------------------------
// W [K][N] fp32 -> Wt [N][K] bf16
// ---------------------------------------------------------------------------
__global__ __launch_bounds__(256)
void wtrans_kernel(const float* __restrict__ W, short* __restrict__ Wt, int K, int N) {
    __shared__ float T[32][33];
    int n0 = blockIdx.x * 32, k0 = blockIdx.y * 32;
    int tx = threadIdx.x & 31, ty = threadIdx.x >> 5;
    #pragma unroll
    for (int i = 0; i < 4; ++i)
        T[ty + i * 8][tx] = W[(size_t)(k0 + ty + i * 8) * N + n0 + tx];
    __syncthreads();
    #pragma unroll
    for (int i = 0; i < 4; ++i)
        Wt[(size_t)(n0 + ty + i * 8) * K + k0 + tx] = f2bf(T[tx][ty + i * 8]);
}

// ---------------------------------------------------------------------------
// V [B,H,S,HD] bf16 -> Vt [B,H,HD,S] bf16
// ---------------------------------------------------------------------------
__global__ __launch_bounds__(256)
void vtrans_kernel(const short* __restrict__ V, short* __restrict__ Vt) {
    __shared__ short T[32][33];
    int p  = blockIdx.z;
    int s0 = blockIdx.x * 32;
    int d0 = blockIdx.y * 32;
    int tx = threadIdx.x & 31, ty = threadIdx.x >> 5;
    const short* Vp  = V  + (size_t)p * S_ * HD_;
    short*       Vtp = Vt + (size_t)p * HD_ * S_;
    #pragma unroll
    for (int i = 0; i < 4; ++i)
        T[ty + i * 8][tx] = Vp[(s0 + ty + i * 8) * HD_ + d0 + tx];
    __syncthreads();
    #pragma unroll
    for (int i = 0; i < 4; ++i)
        Vtp[(size_t)(d0 + ty + i * 8) * S_ + s0 + tx] = T[tx][ty + i * 8];
}

// ---------------------------------------------------------------------------
// bf16 MFMA GEMM, m97 structure: 128x128 tile, BK=32, global_load_lds w=16.
// MODE 0: fp32 C + bias.  MODE 1: scatter Q(scaled)/K/V bf16 [B,H,S,HD].
// ---------------------------------------------------------------------------
template<int MODE>
__global__ __launch_bounds__(256)
void gemm_mfma_kernel(const short* __restrict__ A, const short* __restrict__ Bt,
                      const float* __restrict__ bias, float* __restrict__ Cf,
                      short* __restrict__ Qo, short* __restrict__ Ko, short* __restrict__ Vo,
                      int M, int N, int K) {
    __shared__ __align__(16) short As[128 * 32];
    __shared__ __align__(16) short Bs[128 * 32];

    const int tid  = threadIdx.x;
    const int w    = tid >> 6, lane = tid & 63;
    const int quad = lane >> 4, l16 = lane & 15;
    const int wr = (w >> 1) * 64, wc = (w & 1) * 64;
    const int rowBase = blockIdx.y * 128, colBase = blockIdx.x * 128;

    f32x4 acc[4][4];
    const f32x4 zero = {0.f, 0.f, 0.f, 0.f};
    #pragma unroll
    for (int i = 0; i < 4; ++i)
        #pragma unroll
        for (int j = 0; j < 4; ++j) acc[i][j] = zero;

    const int srow = lane >> 2;        // staging: lane's row within 16-row chunk
    const int scol = (lane & 3) * 8;   // staging: lane's k offset (shorts)

    for (int k0 = 0; k0 < K; k0 += 32) {
        __syncthreads();               // prior frag reads done before overwrite
        gload_lds16(A  + (size_t)(rowBase + w * 16 + srow)      * K + k0 + scol, &As[(w * 16) * 32]);
        gload_lds16(A  + (size_t)(rowBase + 64 + w * 16 + srow) * K + k0 + scol, &As[(64 + w * 16) * 32]);
        gload_lds16(Bt + (size_t)(colBase + w * 16 + srow)      * K + k0 + scol, &Bs[(w * 16) * 32]);
        gload_lds16(Bt + (size_t)(colBase + 64 + w * 16 + srow) * K + k0 + scol, &Bs[(64 + w * 16) * 32]);
        __syncthreads();               // vmcnt(0) drain -> data visible

        bf16x8 af[4], bf[4];
        #pragma unroll
        for (int t = 0; t < 4; ++t) {
            af[t] = *(const bf16x8*)&As[(wr + t * 16 + l16) * 32 + quad * 8];
            bf[t] = *(const bf16x8*)&Bs[(wc + t * 16 + l16) * 32 + quad * 8];
        }
        #pragma unroll
        for (int i = 0; i < 4; ++i)
            #pragma unroll
            for (int j = 0; j < 4; ++j)
                acc[i][j] = MFMA(af[i], bf[j], acc[i][j], 0, 0, 0);
    }

    if (MODE == 0) {
        #pragma unroll
        for (int i = 0; i < 4; ++i) {
            int row = rowBase + wr + i * 16 + quad * 4;
            #pragma unroll
            for (int j = 0; j < 4; ++j) {
                int col = colBase + wc + j * 16 + l16;
                float bv = bias[col];
                #pragma unroll
                for (int r = 0; r < 4; ++r)
                    Cf[(size_t)(row + r) * N + col] = acc[i][j][r] + bv;
            }
        }
    } else {
        #pragma unroll
        for (int j = 0; j < 4; ++j) {
            int col = colBase + wc + j * 16 + l16;
            int sel = col >> 10, cr = col & 1023;
            int h = cr >> 6, d = cr & 63;
            float bv  = bias[col];
            short* dst = (sel == 0) ? Qo : (sel == 1) ? Ko : Vo;
            float  scl = (sel == 0) ? 0.125f : 1.0f;   // softmax scale folded into Q
            #pragma unroll
            for (int i = 0; i < 4; ++i) {
                int row = rowBase + wr + i * 16 + quad * 4;
                #pragma unroll
                for (int r = 0; r < 4; ++r) {
                    int rw = row + r;
                    int bb = rw >> 11, s = rw & 2047;
                    dst[((size_t)(bb * H_ + h) * S_ + s) * HD_ + d] =
                        f2bf((acc[i][j][r] + bv) * scl);
                }
            }
        }
    }
}

// ---------------------------------------------------------------------------
// MFMA causal flash attention v4: shared-LDS K/V staging (amortized across
// 4 waves) + S^T=K*Q^T per-lane softmax + wave-private P^T round trip.
// K tile Ks[kv][d], V^T tile Vs[d][kv], stride 72 (all b128 ops at bank
// floor; P b64 writes 2-way=free). Regs-prefetch: next tile's global loads
// issue right after the barrier, in flight during current tile's compute.
// ---------------------------------------------------------------------------
__global__ __launch_bounds__(256)
void flash_mfma_kernel(const short* __restrict__ Qg, const short* __restrict__ Kg,
                       const short* __restrict__ Vtg, short* __restrict__ Ob) {
    __shared__ __align__(16) short Ks[64][72];
    __shared__ __align__(16) short Vs[64][72];      // Vs[d][kv]
    __shared__ __align__(16) short Ps[4][16][72];   // wave-private P^T / O staging

    const int qt = (int)(gridDim.x - 1) - (int)blockIdx.x;  // heavy blocks first
    const int h = blockIdx.y, b = blockIdx.z;
    const int tid  = threadIdx.x;
    const int w    = tid >> 6, lane = tid & 63;
    const int quad = lane >> 4, l16 = lane & 15;
    const int qBase = qt * 64;
    const size_t plane = (size_t)(b * H_ + h) * S_ * HD_;

    // staging geometry: thread covers rows r0=tid>>3 and r0+32, col8=(tid&7)*8
    const int sr0 = tid >> 3;          // 0..31
    const int sc8 = (tid & 7) * 8;     // 0..56 shorts

    // Q B-frags: n=q=l16, k=d=quad*8+j. Loaded once (already 1/8-scaled).
    const short* Qrow = Qg + plane + (size_t)(qBase + w * 16 + l16) * HD_ + quad * 8;
    const bf16x8 qb0 = *(const bf16x8*)(Qrow);
    const bf16x8 qb1 = *(const bf16x8*)(Qrow + 32);

    f32x4 o[4];
    const f32x4 zero = {0.f, 0.f, 0.f, 0.f};
    #pragma unroll
    for (int i = 0; i < 4; ++i) o[i] = zero;
    float m_r = -3.0e38f, l_r = 0.f;

    short* Pw = &Ps[w][0][0];
    const int q_glob = qBase + w * 16 + l16;

    // prefetch tile kt=0
    uint4 ka, kb, va, vb;
    {
        const short* kp = Kg  + plane + (size_t)sr0 * HD_ + sc8;
        const short* vp = Vtg + plane + (size_t)sr0 * S_  + sc8;
        ka = *(const uint4*)(kp);
        kb = *(const uint4*)(kp + 32 * HD_);
        va = *(const uint4*)(vp);
        vb = *(const uint4*)(vp + (size_t)32 * S_);
    }

    for (int kt = 0; kt <= qt; ++kt) {
        __syncthreads();                       // prev iter's LDS reads done
        *(uint4*)&Ks[sr0][sc8]      = ka;      // implicit vmcnt wait
        *(uint4*)&Ks[sr0 + 32][sc8] = kb;
        *(uint4*)&Vs[sr0][sc8]      = va;
        *(uint4*)&Vs[sr0 + 32][sc8] = vb;
        __syncthreads();                       // tile visible to all waves

        if (kt < qt) {                         // issue next-tile loads now
            const int kb2 = (kt + 1) * 64;
            const short* kp = Kg  + plane + (size_t)(kb2 + sr0) * HD_ + sc8;
            const short* vp = Vtg + plane + (size_t)sr0 * S_ + kb2 + sc8;
            ka = *(const uint4*)(kp);
            kb = *(const uint4*)(kp + 32 * HD_);
            va = *(const uint4*)(vp);
            vb = *(const uint4*)(vp + (size_t)32 * S_);
        }

        // ---- S^T = K Q^T : A=K frag (m=kv=l16, k=d=quad*8+j) from LDS
        f32x4 s[4];
        #pragma unroll
        for (int ct = 0; ct < 4; ++ct) {
            bf16x8 kf0 = *(const bf16x8*)&Ks[ct * 16 + l16][quad * 8];
            bf16x8 kf1 = *(const bf16x8*)&Ks[ct * 16 + l16][32 + quad * 8];
            f32x4 a = zero;
            a = MFMA(kf0, qb0, a, 0, 0, 0);
            a = MFMA(kf1, qb1, a, 0, 0, 0);
            s[ct] = a;
        }

        // ---- V^T A-frags (m=d=l16, k=kv) — issue early, independent of s
        bf16x8 vf[4][2];
        #pragma unroll
        for (int dt = 0; dt < 4; ++dt) {
            vf[dt][0] = *(const bf16x8*)&Vs[dt * 16 + l16][quad * 8];
            vf[dt][1] = *(const bf16x8*)&Vs[dt * 16 + l16][32 + quad * 8];
        }

        // ---- causal mask (diagonal tile only): kv=ct*16+quad*4+r, q=l16
        if (kt == qt) {
            #pragma unroll
            for (int ct = 0; ct < 4; ++ct) {
                int kv = qt * 64 + ct * 16 + quad * 4;
                #pragma unroll
                for (int r = 0; r < 4; ++r)
                    if (kv + r > q_glob) s[ct][r] = -3.0e38f;
            }
        }

        // ---- online softmax: lane owns column q=l16 (16 kv values local)
        float mx = s[0][0];
        #pragma unroll
        for (int ct = 0; ct < 4; ++ct)
            #pragma unroll
            for (int r = 0; r < 4; ++r) mx = fmaxf(mx, s[ct][r]);
        mx = fmaxf(mx, __shfl_xor(mx, 16));
        mx = fmaxf(mx, __shfl_xor(mx, 32));
        float m_new = fmaxf(m_r, mx);
        float alpha = __expf(m_r - m_new);
        float rs = 0.f;
        #pragma unroll
        for (int ct = 0; ct < 4; ++ct) {
            float p0 = __expf(s[ct][0] - m_new);
            float p1 = __expf(s[ct][1] - m_new);
            float p2 = __expf(s[ct][2] - m_new);
            float p3 = __expf(s[ct][3] - m_new);
            rs += (p0 + p1) + (p2 + p3);
            uint2 uu;
            uu.x = pack2bf(p0, p1);
            uu.y = pack2bf(p2, p3);
            *(uint2*)&Pw[l16 * 72 + ct * 16 + quad * 4] = uu;   // P^T [q][kv]
        }
        rs += __shfl_xor(rs, 16);
        rs += __shfl_xor(rs, 32);
        l_r = l_r * alpha + rs;
        m_r = m_new;
        #pragma unroll
        for (int dt = 0; dt < 4; ++dt)
            #pragma unroll
            for (int r = 0; r < 4; ++r) o[dt][r] *= alpha;

        // ---- O^T += V^T P^T : B=P^T frag (k=kv, n=q=l16) from own rows
        #pragma unroll
        for (int kc = 0; kc < 2; ++kc) {
            bf16x8 pb = *(const bf16x8*)&Pw[l16 * 72 + kc * 32 + quad * 8];
            #pragma unroll
            for (int dt = 0; dt < 4; ++dt)
                o[dt] = MFMA(vf[dt][kc], pb, o[dt], 0, 0, 0);
        }
    }

    // ---- epilogue: O^T/l -> LDS transpose (bf16) -> coalesced b128 stores
    float inv_l = 1.0f / l_r;
    #pragma unroll
    for (int dt = 0; dt < 4; ++dt) {
        uint2 uu;
        uu.x = pack2bf(o[dt][0] * inv_l, o[dt][1] * inv_l);
        uu.y = pack2bf(o[dt][2] * inv_l, o[dt][3] * inv_l);
        *(uint2*)&Pw[l16 * 72 + dt * 16 + quad * 4] = uu;   // [q][d]
    }
    __builtin_amdgcn_s_waitcnt(0xC07F);   // lgkmcnt(0): own-wave LDS writes done
    #pragma unroll
    for (int pass = 0; pass < 2; ++pass) {
        int r  = pass * 8 + (lane >> 3);
        int cs = (lane & 7) * 8;
        uint4 vv = *(const uint4*)&Pw[r * 72 + cs];
        *(uint4*)(Ob + (size_t)(b * S_ + qBase + w * 16 + r) * D_ + h * HD_ + cs) = vv;
    }
}

// ---------------------------------------------------------------------------
extern "C" void kernel_launch(void* const* d_in, const int* in_sizes, int n_in,
                              void* d_out, int out_size, void* d_ws, size_t ws_size,
                              hipStream_t stream) {
    const float* x      = (const float*)d_in[0];
    const float* w_attn = (const float*)d_in[1];
    const float* b_attn = (const float*)d_in[2];
    const float* w_proj = (const float*)d_in[3];
    const float* b_proj = (const float*)d_in[4];
    float* out = (float*)d_out;

    char* ws = (char*)d_ws;
    short* xb  = (short*)ws; ws += (size_t)M_ * D_ * 2;
    short* wat = (short*)ws; ws += (size_t)TD_ * D_ * 2;
    short* wpt = (short*)ws; ws += (size_t)D_ * D_ * 2;
    short* qg  = (short*)ws; ws += (size_t)M_ * D_ * 2;
    short* kg  = (short*)ws; ws += (size_t)M_ * D_ * 2;
    short* vg  = (short*)ws; ws += (size_t)M_ * D_ * 2;
    short* vtg = (short*)ws; ws += (size_t)M_ * D_ * 2;
    short* atb = (short*)ws; ws += (size_t)M_ * D_ * 2;

    cast_x_kernel<<<(M_ * D_ / 4 + 255) / 256, 256, 0, stream>>>(x, xb, M_ * D_ / 4);
    wtrans_kernel<<<dim3(TD_ / 32, D_ / 32), 256, 0, stream>>>(w_attn, wat, D_, TD_);
    wtrans_kernel<<<dim3(D_ / 32, D_ / 32), 256, 0, stream>>>(w_proj, wpt, D_, D_);

    gemm_mfma_kernel<1><<<dim3(TD_ / 128, M_ / 128), 256, 0, stream>>>(
        xb, wat, b_attn, nullptr, qg, kg, vg, M_, TD_, D_);

    vtrans_kernel<<<dim3(S_ / 32, HD_ / 32, B_ * H_), 256, 0, stream>>>(vg, vtg);

    flash_mfma_kernel<<<dim3(S_ / 64, H_, B_), 256, 0, stream>>>(qg, kg, vtg, atb);

    gemm_mfma_kernel<0><<<dim3(D_ / 128, M_ / 128), 256, 0, stream>>>(
        atb, wpt, b_proj, out, nullptr, nullptr, nullptr, M_, D_, D_);
}

// Round 5
// 231.699 us; speedup vs baseline: 1.6317x; 1.0018x over previous
//
#include <hip/hip_runtime.h>

// CausalSelfAttention: B=2, S=2048, D=1024, H=16, HD=64
#define B_  2
#define S_  2048
#define D_  1024
#define H_  16
#define HD_ 64
#define TD_ 3072
#define M_  (B_*S_)   // 4096

using bf16x8 = __attribute__((ext_vector_type(8))) short;   // 8 bf16 = 4 VGPRs
using bf16x4 = __attribute__((ext_vector_type(4))) short;   // 4 bf16 = 2 VGPRs
using f32x4  = __attribute__((ext_vector_type(4))) float;   // MFMA C/D

typedef __attribute__((address_space(1))) unsigned int uint_g;
typedef __attribute__((address_space(3))) unsigned int uint_l;

#define MFMA32 __builtin_amdgcn_mfma_f32_16x16x32_bf16

#if defined(__has_builtin)
#if __has_builtin(__builtin_amdgcn_mfma_f32_16x16x16_bf16_1k)
#define MFMA16(a,b,c) __builtin_amdgcn_mfma_f32_16x16x16_bf16_1k(a,b,c,0,0,0)
#define HAVE_MFMA16 1
#elif __has_builtin(__builtin_amdgcn_mfma_f32_16x16x16bf16_1k)
#define MFMA16(a,b,c) __builtin_amdgcn_mfma_f32_16x16x16bf16_1k(a,b,c,0,0,0)
#define HAVE_MFMA16 1
#endif
#endif

static __device__ __forceinline__ short f2bf(float f) {
    unsigned u = __float_as_uint(f);
    u += 0x7FFFu + ((u >> 16) & 1u);   // round-to-nearest-even
    return (short)(u >> 16);
}
static __device__ __forceinline__ unsigned pack2bf(float a, float b) {
    return (unsigned)(unsigned short)f2bf(a) | ((unsigned)(unsigned short)f2bf(b) << 16);
}
// async global->LDS, 16B/lane; LDS dest = uniform base + lane*16 (m97/m104 semantics)
static __device__ __forceinline__ void gload_lds16(const short* g, short* l) {
    __builtin_amdgcn_global_load_lds((const uint_g*)g, (uint_l*)l, 16, 0, 0);
}

// ---------------------------------------------------------------------------
// cast x (fp32) -> bf16
// ---------------------------------------------------------------------------
__global__ void cast_x_kernel(const float* __restrict__ x, short* __restrict__ xb, int n4) {
    int i = blockIdx.x * blockDim.x + threadIdx.x;
    if (i >= n4) return;
    float4 v = *((const float4*)x + i);
    short4 o;
    o.x = f2bf(v.x); o.y = f2bf(v.y); o.z = f2bf(v.z); o.w = f2bf(v.w);
    *((short4*)xb + i) = o;
}

// ---------------------------------------------------------------------------
// W [K][N] fp32 -> Wt [N][K] bf16
// ---------------------------------------------------------------------------
__global__ __launch_bounds__(256)
void wtrans_kernel(const float* __restrict__ W, short* __restrict__ Wt, int K, int N) {
    __shared__ float T[32][33];
    int n0 = blockIdx.x * 32, k0 = blockIdx.y * 32;
    int tx = threadIdx.x & 31, ty = threadIdx.x >> 5;
    #pragma unroll
    for (int i = 0; i < 4; ++i)
        T[ty + i * 8][tx] = W[(size_t)(k0 + ty + i * 8) * N + n0 + tx];
    __syncthreads();
    #pragma unroll
    for (int i = 0; i < 4; ++i)
        Wt[(size_t)(n0 + ty + i * 8) * K + k0 + tx] = f2bf(T[tx][ty + i * 8]);
}

// ---------------------------------------------------------------------------
// V [B,H,S,HD] bf16 -> Vt [B,H,HD,S] bf16
// ---------------------------------------------------------------------------
__global__ __launch_bounds__(256)
void vtrans_kernel(const short* __restrict__ V, short* __restrict__ Vt) {
    __shared__ short T[32][33];
    int p  = blockIdx.z;
    int s0 = blockIdx.x * 32;
    int d0 = blockIdx.y * 32;
    int tx = threadIdx.x & 31, ty = threadIdx.x >> 5;
    const short* Vp  = V  + (size_t)p * S_ * HD_;
    short*       Vtp = Vt + (size_t)p * HD_ * S_;
    #pragma unroll
    for (int i = 0; i < 4; ++i)
        T[ty + i * 8][tx] = Vp[(s0 + ty + i * 8) * HD_ + d0 + tx];
    __syncthreads();
    #pragma unroll
    for (int i = 0; i < 4; ++i)
        Vtp[(size_t)(d0 + ty + i * 8) * S_ + s0 + tx] = T[tx][ty + i * 8];
}

// ---------------------------------------------------------------------------
// bf16 MFMA GEMM, m97 structure: 128x128 tile, BK=32, global_load_lds w=16.
// MODE 0: fp32 C + bias.  MODE 1: scatter Q(scaled)/K/V bf16 [B,H,S,HD].
// ---------------------------------------------------------------------------
template<int MODE>
__global__ __launch_bounds__(256)
void gemm_mfma_kernel(const short* __restrict__ A, const short* __restrict__ Bt,
                      const float* __restrict__ bias, float* __restrict__ Cf,
                      short* __restrict__ Qo, short* __restrict__ Ko, short* __restrict__ Vo,
                      int M, int N, int K) {
    __shared__ __align__(16) short As[128 * 32];
    __shared__ __align__(16) short Bs[128 * 32];

    const int tid  = threadIdx.x;
    const int w    = tid >> 6, lane = tid & 63;
    const int quad = lane >> 4, l16 = lane & 15;
    const int wr = (w >> 1) * 64, wc = (w & 1) * 64;
    const int rowBase = blockIdx.y * 128, colBase = blockIdx.x * 128;

    f32x4 acc[4][4];
    const f32x4 zero = {0.f, 0.f, 0.f, 0.f};
    #pragma unroll
    for (int i = 0; i < 4; ++i)
        #pragma unroll
        for (int j = 0; j < 4; ++j) acc[i][j] = zero;

    const int srow = lane >> 2;
    const int scol = (lane & 3) * 8;

    for (int k0 = 0; k0 < K; k0 += 32) {
        __syncthreads();
        gload_lds16(A  + (size_t)(rowBase + w * 16 + srow)      * K + k0 + scol, &As[(w * 16) * 32]);
        gload_lds16(A  + (size_t)(rowBase + 64 + w * 16 + srow) * K + k0 + scol, &As[(64 + w * 16) * 32]);
        gload_lds16(Bt + (size_t)(colBase + w * 16 + srow)      * K + k0 + scol, &Bs[(w * 16) * 32]);
        gload_lds16(Bt + (size_t)(colBase + 64 + w * 16 + srow) * K + k0 + scol, &Bs[(64 + w * 16) * 32]);
        __syncthreads();

        bf16x8 af[4], bf[4];
        #pragma unroll
        for (int t = 0; t < 4; ++t) {
            af[t] = *(const bf16x8*)&As[(wr + t * 16 + l16) * 32 + quad * 8];
            bf[t] = *(const bf16x8*)&Bs[(wc + t * 16 + l16) * 32 + quad * 8];
        }
        #pragma unroll
        for (int i = 0; i < 4; ++i)
            #pragma unroll
            for (int j = 0; j < 4; ++j)
                acc[i][j] = MFMA32(af[i], bf[j], acc[i][j], 0, 0, 0);
    }

    if (MODE == 0) {
        #pragma unroll
        for (int i = 0; i < 4; ++i) {
            int row = rowBase + wr + i * 16 + quad * 4;
            #pragma unroll
            for (int j = 0; j < 4; ++j) {
                int col = colBase + wc + j * 16 + l16;
                float bv = bias[col];
                #pragma unroll
                for (int r = 0; r < 4; ++r)
                    Cf[(size_t)(row + r) * N + col] = acc[i][j][r] + bv;
            }
        }
    } else {
        #pragma unroll
        for (int j = 0; j < 4; ++j) {
            int col = colBase + wc + j * 16 + l16;
            int sel = col >> 10, cr = col & 1023;
            int h = cr >> 6, d = cr & 63;
            float bv  = bias[col];
            short* dst = (sel == 0) ? Qo : (sel == 1) ? Ko : Vo;
            float  scl = (sel == 0) ? 0.125f : 1.0f;   // softmax scale folded into Q
            #pragma unroll
            for (int i = 0; i < 4; ++i) {
                int row = rowBase + wr + i * 16 + quad * 4;
                #pragma unroll
                for (int r = 0; r < 4; ++r) {
                    int rw = row + r;
                    int bb = rw >> 11, s = rw & 2047;
                    dst[((size_t)(bb * H_ + h) * S_ + s) * HD_ + d] =
                        f2bf((acc[i][j][r] + bv) * scl);
                }
            }
        }
    }
}

// ---------------------------------------------------------------------------
// MFMA causal flash attention v5: 512 threads (8 waves), BQ=128, BKV=64.
// Shared K/V staging amortized over 8 waves; S^T=K*Q^T per-lane softmax;
// PV via 16x16x16 MFMA feeding P^T straight from the S^T C-layout
// (row=kv=quad*4+r matches the K=16 B-operand k=quad*4+j) -- no LDS round
// trip. Register prefetch of next K/V tile. Wave-level early-out above
// the diagonal. Epilogue transposes O^T through the (dead) K/V LDS.
// ---------------------------------------------------------------------------
__global__ __launch_bounds__(512, 6)
void flash_mfma_kernel(const short* __restrict__ Qg, const short* __restrict__ Kg,
                       const short* __restrict__ Vtg, short* __restrict__ Ob) {
    __shared__ __align__(16) short KV[128][72];   // rows 0..63 = K[kv][d], 64..127 = Vt[d][kv]
#ifndef HAVE_MFMA16
    __shared__ __align__(16) short Ps[8][16][72];
#endif

    const int qi = (int)(gridDim.x - 1) - (int)blockIdx.x;  // heavy blocks first
    const int h = blockIdx.y, b = blockIdx.z;
    const int tid  = threadIdx.x;
    const int w    = tid >> 6, lane = tid & 63;
    const int quad = lane >> 4, l16 = lane & 15;
    const int qBase = qi * 128;
    const size_t plane = (size_t)(b * H_ + h) * S_ * HD_;

    // staging: 512 threads x 16B = one full 64x64 bf16 tile per buffer
    const int sr  = tid >> 3;          // 0..63
    const int sc8 = (tid & 7) * 8;     // 0..56 shorts

    // Q B-frags: n=q=l16, k=d=quad*8+j. Loaded once (already 1/8-scaled).
    const short* Qrow = Qg + plane + (size_t)(qBase + w * 16 + l16) * HD_ + quad * 8;
    const bf16x8 qb0 = *(const bf16x8*)(Qrow);
    const bf16x8 qb1 = *(const bf16x8*)(Qrow + 32);

    f32x4 o[4];
    const f32x4 zero = {0.f, 0.f, 0.f, 0.f};
    #pragma unroll
    for (int i = 0; i < 4; ++i) o[i] = zero;
    float m_r = -3.0e38f, l_r = 0.f;

    const int q_glob = qBase + w * 16 + l16;
    const int q_wave_max = qBase + w * 16 + 15;
    const int nkt = 2 * qi + 2;

    // prefetch tile kt=0
    uint4 ka, va;
    {
        ka = *(const uint4*)(Kg  + plane + (size_t)sr * HD_ + sc8);
        va = *(const uint4*)(Vtg + plane + (size_t)sr * S_  + sc8);
    }

    for (int kt = 0; kt < nkt; ++kt) {
        __syncthreads();                       // prev iter's LDS reads done
        *(uint4*)&KV[sr][sc8]      = ka;       // implicit vmcnt wait
        *(uint4*)&KV[64 + sr][sc8] = va;
        __syncthreads();                       // tile visible to all waves

        if (kt + 1 < nkt) {                    // issue next-tile loads now
            const int kb2 = (kt + 1) * 64;
            ka = *(const uint4*)(Kg  + plane + (size_t)(kb2 + sr) * HD_ + sc8);
            va = *(const uint4*)(Vtg + plane + (size_t)sr * S_ + kb2 + sc8);
        }

        const int kBase = kt * 64;
        if (kBase > q_wave_max) continue;      // wave entirely above diagonal

        // ---- S^T = K Q^T : A=K frag (m=kv=l16, k=d=quad*8+j) from LDS
        f32x4 s[4];
        #pragma unroll
        for (int ct = 0; ct < 4; ++ct) {
            bf16x8 kf0 = *(const bf16x8*)&KV[ct * 16 + l16][quad * 8];
            bf16x8 kf1 = *(const bf16x8*)&KV[ct * 16 + l16][32 + quad * 8];
            f32x4 a = zero;
            a = MFMA32(kf0, qb0, a, 0, 0, 0);
            a = MFMA32(kf1, qb1, a, 0, 0, 0);
            s[ct] = a;
        }

        // ---- causal mask: kv=kBase+ct*16+quad*4+r vs q=l16 column
        if (kBase + 63 > qBase + w * 16) {
            #pragma unroll
            for (int ct = 0; ct < 4; ++ct) {
                int kv = kBase + ct * 16 + quad * 4;
                #pragma unroll
                for (int r = 0; r < 4; ++r)
                    if (kv + r > q_glob) s[ct][r] = -3.0e38f;
            }
        }

        // ---- online softmax: lane owns column q=l16 (16 kv values local)
        float mx = s[0][0];
        #pragma unroll
        for (int ct = 0; ct < 4; ++ct)
            #pragma unroll
            for (int r = 0; r < 4; ++r) mx = fmaxf(mx, s[ct][r]);
        mx = fmaxf(mx, __shfl_xor(mx, 16));
        mx = fmaxf(mx, __shfl_xor(mx, 32));
        float m_new = fmaxf(m_r, mx);
        float alpha = __expf(m_r - m_new);
        float rs = 0.f;
        float p[4][4];
        #pragma unroll
        for (int ct = 0; ct < 4; ++ct) {
            #pragma unroll
            for (int r = 0; r < 4; ++r) {
                p[ct][r] = __expf(s[ct][r] - m_new);
                rs += p[ct][r];
            }
        }
        rs += __shfl_xor(rs, 16);
        rs += __shfl_xor(rs, 32);
        l_r = l_r * alpha + rs;
        m_r = m_new;
        #pragma unroll
        for (int dt = 0; dt < 4; ++dt)
            #pragma unroll
            for (int r = 0; r < 4; ++r) o[dt][r] *= alpha;

#ifdef HAVE_MFMA16
        // ---- O^T += V^T P^T via 16x16x16: P^T is already in B-layout
        #pragma unroll
        for (int ct = 0; ct < 4; ++ct) {
            unsigned lo = pack2bf(p[ct][0], p[ct][1]);
            unsigned hi = pack2bf(p[ct][2], p[ct][3]);
            bf16x4 pb;
            *(unsigned*)&pb    = lo;
            *((unsigned*)&pb + 1) = hi;
            #pragma unroll
            for (int dt = 0; dt < 4; ++dt) {
                bf16x4 vfr = *(const bf16x4*)&KV[64 + dt * 16 + l16][ct * 16 + quad * 4];
                o[dt] = MFMA16(vfr, pb, o[dt]);
            }
        }
#else
        // ---- fallback: P round trip through wave-private LDS
        short* Pw = &Ps[w][0][0];
        #pragma unroll
        for (int ct = 0; ct < 4; ++ct) {
            uint2 uu;
            uu.x = pack2bf(p[ct][0], p[ct][1]);
            uu.y = pack2bf(p[ct][2], p[ct][3]);
            *(uint2*)&Pw[l16 * 72 + ct * 16 + quad * 4] = uu;
        }
        __builtin_amdgcn_s_waitcnt(0xC07F);   // lgkmcnt(0)
        #pragma unroll
        for (int kc = 0; kc < 2; ++kc) {
            bf16x8 pb = *(const bf16x8*)&Pw[l16 * 72 + kc * 32 + quad * 8];
            #pragma unroll
            for (int dt = 0; dt < 4; ++dt) {
                bf16x8 vf8 = *(const bf16x8*)&KV[64 + dt * 16 + l16][kc * 32 + quad * 8];
                o[dt] = MFMA32(vf8, pb, o[dt], 0, 0, 0);
            }
        }
#endif
    }

    // ---- epilogue: O^T/l -> LDS transpose (reuse KV) -> coalesced stores
    __syncthreads();                           // all KV readers done
    float inv_l = 1.0f / l_r;
    short* Pw = &KV[w * 16][0];
    #pragma unroll
    for (int dt = 0; dt < 4; ++dt) {
        uint2 uu;
        uu.x = pack2bf(o[dt][0] * inv_l, o[dt][1] * inv_l);
        uu.y = pack2bf(o[dt][2] * inv_l, o[dt][3] * inv_l);
        *(uint2*)&Pw[l16 * 72 + dt * 16 + quad * 4] = uu;   // [q][d]
    }
    __builtin_amdgcn_s_waitcnt(0xC07F);        // own-wave LDS writes done
    #pragma unroll
    for (int pass = 0; pass < 2; ++pass) {
        int r  = pass * 8 + (lane >> 3);
        int cs = (lane & 7) * 8;
        uint4 vv = *(const uint4*)&Pw[r * 72 + cs];
        *(uint4*)(Ob + (size_t)(b * S_ + qBase + w * 16 + r) * D_ + h * HD_ + cs) = vv;
    }
}

// ---------------------------------------------------------------------------
extern "C" void kernel_launch(void* const* d_in, const int* in_sizes, int n_in,
                              void* d_out, int out_size, void* d_ws, size_t ws_size,
                              hipStream_t stream) {
    const float* x      = (const float*)d_in[0];
    const float* w_attn = (const float*)d_in[1];
    const float* b_attn = (const float*)d_in[2];
    const float* w_proj = (const float*)d_in[3];
    const float* b_proj = (const float*)d_in[4];
    float* out = (float*)d_out;

    char* ws = (char*)d_ws;
    short* xb  = (short*)ws; ws += (size_t)M_ * D_ * 2;
    short* wat = (short*)ws; ws += (size_t)TD_ * D_ * 2;
    short* wpt = (short*)ws; ws += (size_t)D_ * D_ * 2;
    short* qg  = (short*)ws; ws += (size_t)M_ * D_ * 2;
    short* kg  = (short*)ws; ws += (size_t)M_ * D_ * 2;
    short* vg  = (short*)ws; ws += (size_t)M_ * D_ * 2;
    short* vtg = (short*)ws; ws += (size_t)M_ * D_ * 2;
    short* atb = (short*)ws; ws += (size_t)M_ * D_ * 2;

    cast_x_kernel<<<(M_ * D_ / 4 + 255) / 256, 256, 0, stream>>>(x, xb, M_ * D_ / 4);
    wtrans_kernel<<<dim3(TD_ / 32, D_ / 32), 256, 0, stream>>>(w_attn, wat, D_, TD_);
    wtrans_kernel<<<dim3(D_ / 32, D_ / 32), 256, 0, stream>>>(w_proj, wpt, D_, D_);

    gemm_mfma_kernel<1><<<dim3(TD_ / 128, M_ / 128), 256, 0, stream>>>(
        xb, wat, b_attn, nullptr, qg, kg, vg, M_, TD_, D_);

    vtrans_kernel<<<dim3(S_ / 32, HD_ / 32, B_ * H_), 256, 0, stream>>>(vg, vtg);

    flash_mfma_kernel<<<dim3(S_ / 128, H_, B_), 512, 0, stream>>>(qg, kg, vtg, atb);

    gemm_mfma_kernel<0><<<dim3(D_ / 128, M_ / 128), 256, 0, stream>>>(
        atb, wpt, b_proj, out, nullptr, nullptr, nullptr, M_, D_, D_);
}